// Round 1
// baseline (963.669 us; speedup 1.0000x reference)
//
#include <hip/hip_runtime.h>

#define N_FEAT 64
#define OUT_FEAT 32

// One wave (64 lanes) per edge: lane = feature index.
// Reads feat[src] row (256B coalesced), atomicAdds into agg[dst] row.
// Lane 0 optionally bumps deg[dst] by 1.0.
__global__ void scatter_kernel(const float* __restrict__ feat,
                               const int* __restrict__ src,
                               const int* __restrict__ dst,
                               float* __restrict__ agg,
                               float* __restrict__ deg,
                               int n_edges, int compute_deg) {
    int wave = blockIdx.x * (blockDim.x >> 6) + (threadIdx.x >> 6);
    int lane = threadIdx.x & 63;
    if (wave >= n_edges) return;
    int s = src[wave];
    int d = dst[wave];
    float v = feat[(size_t)s * N_FEAT + lane];
    atomicAdd(&agg[(size_t)d * N_FEAT + lane], v);
    if (compute_deg && lane == 0) atomicAdd(&deg[d], 1.0f);
}

// h[i][f] = relu( sum_k x[i][k]*Ws[k][f] + (agg[i][k]/max(deg,1))*Wn[k][f] + b[f] )
// 256 threads = 4 waves; each wave owns one node per iteration; lane = out feature.
__global__ void layer1_kernel(const float* __restrict__ x,
                              const float* __restrict__ agg,
                              const float* __restrict__ deg,
                              const float* __restrict__ Ws,   // [64][64]
                              const float* __restrict__ Wn,   // [64][64]
                              const float* __restrict__ b,    // [64]
                              float* __restrict__ h, int n) {
    __shared__ float sWs[64 * 64];
    __shared__ float sWn[64 * 64];
    for (int i = threadIdx.x; i < 64 * 64; i += blockDim.x) {
        sWs[i] = Ws[i];
        sWn[i] = Wn[i];
    }
    __syncthreads();

    int lane = threadIdx.x & 63;
    int wid  = threadIdx.x >> 6;
    __shared__ float sx[4][64];
    __shared__ float sa[4][64];
    float bias = b[lane];

    for (int node = blockIdx.x * 4 + wid; node < n; node += gridDim.x * 4) {
        float inv = 1.0f / fmaxf(deg[node], 1.0f);
        sx[wid][lane] = x[(size_t)node * N_FEAT + lane];
        sa[wid][lane] = agg[(size_t)node * N_FEAT + lane] * inv;
        // same-wave LDS write->read; compiler inserts lgkmcnt, no barrier needed
        float acc = bias;
#pragma unroll
        for (int k = 0; k < 64; k++) {
            acc += sx[wid][k] * sWs[k * 64 + lane];
            acc += sa[wid][k] * sWn[k * 64 + lane];
        }
        h[(size_t)node * N_FEAT + lane] = fmaxf(acc, 0.0f);
    }
}

// out[i][f] = sum_k h[i][k]*Ws[k][f] + (agg[i][k]/max(deg,1))*Wn[k][f] + b[f]
// OUT=32, so each wave handles 2 nodes: sub = lane>>5, f = lane&31.
__global__ void layer2_kernel(const float* __restrict__ h,
                              const float* __restrict__ agg,
                              const float* __restrict__ deg,
                              const float* __restrict__ Ws,   // [64][32]
                              const float* __restrict__ Wn,   // [64][32]
                              const float* __restrict__ b,    // [32]
                              float* __restrict__ out, int n) {
    __shared__ float sWs[64 * 32];
    __shared__ float sWn[64 * 32];
    for (int i = threadIdx.x; i < 64 * 32; i += blockDim.x) {
        sWs[i] = Ws[i];
        sWn[i] = Wn[i];
    }
    __syncthreads();

    int lane = threadIdx.x & 63;
    int wid  = threadIdx.x >> 6;
    int f    = lane & 31;
    int sub  = lane >> 5;
    __shared__ float sh[4][2][64];
    __shared__ float sa[4][2][64];
    float bias = b[f];

    for (int base = blockIdx.x * 8 + wid * 2; base < n; base += gridDim.x * 8) {
        int node = base + sub;
        bool valid = node < n;
        int nd = valid ? node : (n - 1);
        float inv = 1.0f / fmaxf(deg[nd], 1.0f);
        sh[wid][sub][f]      = h[(size_t)nd * N_FEAT + f];
        sh[wid][sub][f + 32] = h[(size_t)nd * N_FEAT + f + 32];
        sa[wid][sub][f]      = agg[(size_t)nd * N_FEAT + f] * inv;
        sa[wid][sub][f + 32] = agg[(size_t)nd * N_FEAT + f + 32] * inv;
        float acc = bias;
#pragma unroll
        for (int k = 0; k < 64; k++) {
            acc += sh[wid][sub][k] * sWs[k * 32 + f];
            acc += sa[wid][sub][k] * sWn[k * 32 + f];
        }
        if (valid) out[(size_t)node * OUT_FEAT + f] = acc;
    }
}

extern "C" void kernel_launch(void* const* d_in, const int* in_sizes, int n_in,
                              void* d_out, int out_size, void* d_ws, size_t ws_size,
                              hipStream_t stream) {
    const float* x   = (const float*)d_in[0];
    const int*   src = (const int*)d_in[1];
    const int*   dst = (const int*)d_in[2];
    const float* Ws1 = (const float*)d_in[3];
    const float* Wn1 = (const float*)d_in[4];
    const float* b1  = (const float*)d_in[5];
    const float* Ws2 = (const float*)d_in[6];
    const float* Wn2 = (const float*)d_in[7];
    const float* b2  = (const float*)d_in[8];
    float* out = (float*)d_out;

    int n_nodes = in_sizes[0] / N_FEAT;   // 100000
    int n_edges = in_sizes[1];            // 1600000

    // Workspace layout: [deg: padded N floats][agg: N*64 floats][h: N*64 floats]
    size_t deg_bytes = ((size_t)n_nodes * 4 + 4095) & ~(size_t)4095;
    size_t agg_bytes = (size_t)n_nodes * N_FEAT * 4;
    char* ws = (char*)d_ws;
    float* deg = (float*)ws;
    float* agg = (float*)(ws + deg_bytes);
    float* h   = (float*)(ws + deg_bytes + agg_bytes);

    // Zero deg + agg for layer 1
    hipMemsetAsync(ws, 0, deg_bytes + agg_bytes, stream);

    int scatter_blocks = (n_edges + 3) / 4;   // 4 waves (edges) per 256-thread block
    scatter_kernel<<<scatter_blocks, 256, 0, stream>>>(x, src, dst, agg, deg, n_edges, 1);

    int l1_blocks = (n_nodes + 3) / 4;
    layer1_kernel<<<l1_blocks, 256, 0, stream>>>(x, agg, deg, Ws1, Wn1, b1, h, n_nodes);

    // Re-zero agg for layer 2
    hipMemsetAsync((void*)agg, 0, agg_bytes, stream);
    scatter_kernel<<<scatter_blocks, 256, 0, stream>>>(h, src, dst, agg, nullptr, n_edges, 0);

    int l2_blocks = (n_nodes + 7) / 8;
    layer2_kernel<<<l2_blocks, 256, 0, stream>>>(h, agg, deg, Ws2, Wn2, b2, out, n_nodes);
}

// Round 2
// 674.037 us; speedup vs baseline: 1.4297x; 1.4297x over previous
//
#include <hip/hip_runtime.h>

#define NF 64     // IN == HID
#define OF 32     // OUT

// ---------------- CSR build ----------------

__global__ void count_kernel(const int* __restrict__ dst, int* __restrict__ cnt, int n_edges) {
    int e = blockIdx.x * blockDim.x + threadIdx.x;
    if (e < n_edges) atomicAdd(&cnt[dst[e]], 1);
}

// Single-block exclusive scan: 1024 threads, each owns a contiguous chunk.
__global__ void scan_kernel(const int* __restrict__ cnt, int* __restrict__ row_ptr, int n) {
    __shared__ int ssum[1024];
    int tid = threadIdx.x;
    int chunk = (n + (int)blockDim.x - 1) / (int)blockDim.x;
    int start = tid * chunk;
    int end = min(start + chunk, n);
    int s = 0;
    for (int i = start; i < end; i++) s += cnt[i];
    ssum[tid] = s;
    __syncthreads();
    // Hillis-Steele inclusive scan over thread sums
    for (int off = 1; off < 1024; off <<= 1) {
        int v = (tid >= (int)off) ? ssum[tid - off] : 0;
        __syncthreads();
        ssum[tid] += v;
        __syncthreads();
    }
    int run = (tid == 0) ? 0 : ssum[tid - 1];
    for (int i = start; i < end; i++) {
        row_ptr[i] = run;
        run += cnt[i];
    }
    if (tid == (int)blockDim.x - 1) row_ptr[n] = run;
}

__global__ void fill_kernel(const int* __restrict__ src, const int* __restrict__ dst,
                            const int* __restrict__ row_ptr, int* __restrict__ cursor,
                            int* __restrict__ csr, int n_edges) {
    int e = blockIdx.x * blockDim.x + threadIdx.x;
    if (e >= n_edges) return;
    int d = dst[e];
    int slot = atomicAdd(&cursor[d], 1);
    csr[row_ptr[d] + slot] = src[e];
}

// ---------------- dense transform: u1 = x @ Ws1 + b1 ----------------

__global__ void transform1_kernel(const float* __restrict__ x,
                                  const float* __restrict__ Ws,  // [64][64]
                                  const float* __restrict__ b,   // [64]
                                  float* __restrict__ u1, int n) {
    __shared__ float sW[NF * NF];
    for (int i = threadIdx.x; i < NF * NF; i += blockDim.x) sW[i] = Ws[i];
    __syncthreads();
    int lane = threadIdx.x & 63, wid = threadIdx.x >> 6;
    __shared__ float sx[4][NF];
    float bias = b[lane];
    int node = blockIdx.x * 4 + wid;
    if (node >= n) return;
    sx[wid][lane] = x[(size_t)node * NF + lane];
    float acc = bias;
#pragma unroll
    for (int k = 0; k < NF; k++) acc += sx[wid][k] * sW[k * NF + lane];
    u1[(size_t)node * NF + lane] = acc;
}

// ---------------- gather1: h = relu(u1 + (mean x[src]) @ Wn1); u2 = h@Ws2+b2 -> out ----------------

__global__ void gather1_kernel(const float* __restrict__ x,
                               const int* __restrict__ row_ptr, const int* __restrict__ csr,
                               const float* __restrict__ Wn1,  // [64][64]
                               const float* __restrict__ Ws2,  // [64][32]
                               const float* __restrict__ b2,   // [32]
                               float* __restrict__ A,          // in: u1, out: h  (N x 64)
                               float* __restrict__ out,        // d_out (N x 32): u2 written here
                               int n) {
    __shared__ float sWn[NF * NF];
    __shared__ float sWs2[NF * OF];
    for (int i = threadIdx.x; i < NF * NF; i += blockDim.x) sWn[i] = Wn1[i];
    for (int i = threadIdx.x; i < NF * OF; i += blockDim.x) sWs2[i] = Ws2[i];
    __syncthreads();
    int lane = threadIdx.x & 63, wid = threadIdx.x >> 6;
    int f = lane & 31, half = lane >> 5;
    __shared__ float sa[4][NF];
    __shared__ float sh[4][NF];
    float bias2 = b2[f];

    int node = blockIdx.x * 4 + wid;
    if (node >= n) return;

    int beg = row_ptr[node], end = row_ptr[node + 1];
    float acc = 0.f;
    for (int base = beg; base < end; base += 64) {
        int m = min(64, end - base);
        int idx = (lane < m) ? csr[base + lane] : 0;
        int j = 0;
        for (; j + 1 < m; j += 2) {
            int s0 = __shfl(idx, j);
            int s1 = __shfl(idx, j + 1);
            float v0 = x[(size_t)s0 * NF + lane];
            float v1 = x[(size_t)s1 * NF + lane];
            acc += v0;
            acc += v1;
        }
        if (j < m) {
            int s0 = __shfl(idx, j);
            acc += x[(size_t)s0 * NF + lane];
        }
    }
    float inv = 1.0f / (float)max(end - beg, 1);
    sa[wid][lane] = acc * inv;

    // h = relu(u1 + agg @ Wn1)
    float hacc = A[(size_t)node * NF + lane];
#pragma unroll
    for (int k = 0; k < NF; k++) hacc += sa[wid][k] * sWn[k * NF + lane];
    float h = fmaxf(hacc, 0.f);
    A[(size_t)node * NF + lane] = h;   // store h over u1 (only this wave touches row `node`)

    // u2 = h @ Ws2 + b2  (32 outputs, split the k-sum across the two half-waves)
    sh[wid][lane] = h;
    float uacc = (half == 0) ? bias2 : 0.f;
#pragma unroll
    for (int kk = 0; kk < 32; kk++) {
        int k = half * 32 + kk;
        uacc += sh[wid][k] * sWs2[k * OF + f];
    }
    uacc += __shfl_xor(uacc, 32);
    if (half == 0) out[(size_t)node * OF + f] = uacc;
}

// ---------------- gather2: out += (mean h[src]) @ Wn2 ----------------

__global__ void gather2_kernel(const float* __restrict__ h,   // region A
                               const int* __restrict__ row_ptr, const int* __restrict__ csr,
                               const float* __restrict__ Wn2,  // [64][32]
                               float* __restrict__ out, int n) {
    __shared__ float sW[NF * OF];
    for (int i = threadIdx.x; i < NF * OF; i += blockDim.x) sW[i] = Wn2[i];
    __syncthreads();
    int lane = threadIdx.x & 63, wid = threadIdx.x >> 6;
    int f = lane & 31, half = lane >> 5;
    __shared__ float sa[4][NF];

    int node = blockIdx.x * 4 + wid;
    if (node >= n) return;

    int beg = row_ptr[node], end = row_ptr[node + 1];
    float acc = 0.f;
    for (int base = beg; base < end; base += 64) {
        int m = min(64, end - base);
        int idx = (lane < m) ? csr[base + lane] : 0;
        int j = 0;
        for (; j + 1 < m; j += 2) {
            int s0 = __shfl(idx, j);
            int s1 = __shfl(idx, j + 1);
            float v0 = h[(size_t)s0 * NF + lane];
            float v1 = h[(size_t)s1 * NF + lane];
            acc += v0;
            acc += v1;
        }
        if (j < m) {
            int s0 = __shfl(idx, j);
            acc += h[(size_t)s0 * NF + lane];
        }
    }
    float inv = 1.0f / (float)max(end - beg, 1);
    sa[wid][lane] = acc * inv;

    float oacc = 0.f;
#pragma unroll
    for (int kk = 0; kk < 32; kk++) {
        int k = half * 32 + kk;
        oacc += sa[wid][k] * sW[k * OF + f];
    }
    oacc += __shfl_xor(oacc, 32);
    if (half == 0) out[(size_t)node * OF + f] += oacc;
}

// ---------------- launch ----------------

extern "C" void kernel_launch(void* const* d_in, const int* in_sizes, int n_in,
                              void* d_out, int out_size, void* d_ws, size_t ws_size,
                              hipStream_t stream) {
    const float* x   = (const float*)d_in[0];
    const int*   src = (const int*)d_in[1];
    const int*   dst = (const int*)d_in[2];
    const float* Ws1 = (const float*)d_in[3];
    const float* Wn1 = (const float*)d_in[4];
    const float* b1  = (const float*)d_in[5];
    const float* Ws2 = (const float*)d_in[6];
    const float* Wn2 = (const float*)d_in[7];
    const float* b2  = (const float*)d_in[8];
    float* out = (float*)d_out;

    int n_nodes = in_sizes[0] / NF;   // 100000
    int n_edges = in_sizes[1];        // 1600000

    // Workspace layout (4 KB aligned chunks):
    //   cnt/cursor: N ints | row_ptr: N+1 ints | csr: E ints | A: N*64 floats (u1 -> h)
    auto align4k = [](size_t v) { return (v + 4095) & ~(size_t)4095; };
    char* ws = (char*)d_ws;
    size_t cnt_b = align4k((size_t)n_nodes * 4);
    size_t rp_b  = align4k(((size_t)n_nodes + 1) * 4);
    size_t csr_b = align4k((size_t)n_edges * 4);
    int* cnt     = (int*)ws;
    int* row_ptr = (int*)(ws + cnt_b);
    int* csr     = (int*)(ws + cnt_b + rp_b);
    float* A     = (float*)(ws + cnt_b + rp_b + csr_b);

    int eblocks = (n_edges + 255) / 256;
    int nblocks = (n_nodes + 3) / 4;

    // CSR build
    hipMemsetAsync(cnt, 0, (size_t)n_nodes * 4, stream);
    count_kernel<<<eblocks, 256, 0, stream>>>(dst, cnt, n_edges);
    scan_kernel<<<1, 1024, 0, stream>>>(cnt, row_ptr, n_nodes);
    hipMemsetAsync(cnt, 0, (size_t)n_nodes * 4, stream);   // reuse as cursor
    fill_kernel<<<eblocks, 256, 0, stream>>>(src, dst, row_ptr, cnt, csr, n_edges);

    // u1 = x@Ws1 + b1
    transform1_kernel<<<nblocks, 256, 0, stream>>>(x, Ws1, b1, A, n_nodes);

    // h = relu(u1 + mean_agg(x)@Wn1); u2 = h@Ws2 + b2 -> out
    gather1_kernel<<<nblocks, 256, 0, stream>>>(x, row_ptr, csr, Wn1, Ws2, b2, A, out, n_nodes);

    // out += mean_agg(h)@Wn2
    gather2_kernel<<<nblocks, 256, 0, stream>>>(A, row_ptr, csr, Wn2, out, n_nodes);
}

// Round 3
// 523.902 us; speedup vs baseline: 1.8394x; 1.2866x over previous
//
#include <hip/hip_runtime.h>

#define NF 64     // IN == HID
#define OF 32     // OUT

// ---------------- CSR build ----------------

__global__ void count_kernel(const int* __restrict__ dst, int* __restrict__ cnt, int n_edges) {
    int e = blockIdx.x * blockDim.x + threadIdx.x;
    if (e < n_edges) atomicAdd(&cnt[dst[e]], 1);
}

// Single-block exclusive scan: 1024 threads, each owns a contiguous chunk.
__global__ void scan_kernel(const int* __restrict__ cnt, int* __restrict__ row_ptr, int n) {
    __shared__ int ssum[1024];
    int tid = threadIdx.x;
    int chunk = (n + (int)blockDim.x - 1) / (int)blockDim.x;
    int start = tid * chunk;
    int end = min(start + chunk, n);
    int s = 0;
    for (int i = start; i < end; i++) s += cnt[i];
    ssum[tid] = s;
    __syncthreads();
    for (int off = 1; off < 1024; off <<= 1) {
        int v = (tid >= (int)off) ? ssum[tid - off] : 0;
        __syncthreads();
        ssum[tid] += v;
        __syncthreads();
    }
    int run = (tid == 0) ? 0 : ssum[tid - 1];
    for (int i = start; i < end; i++) {
        row_ptr[i] = run;
        run += cnt[i];
    }
    if (tid == (int)blockDim.x - 1) row_ptr[n] = run;
}

__global__ void fill_kernel(const int* __restrict__ src, const int* __restrict__ dst,
                            const int* __restrict__ row_ptr, int* __restrict__ cursor,
                            int* __restrict__ csr, int n_edges) {
    int e = blockIdx.x * blockDim.x + threadIdx.x;
    if (e >= n_edges) return;
    int d = dst[e];
    int slot = atomicAdd(&cursor[d], 1);
    csr[row_ptr[d] + slot] = src[e];
}

// ---------------- gather+GEMM helpers ----------------
// Wave gather layout: eg = lane>>4 (edge subgroup 0..3), fq = (lane&15)*4 (feature quad).
// Each round loads 4 edges x float4; 2 rounds in flight (8 edges).
// Returns: lanes 0..15 hold the row-sum quad for features fq..fq+3 in acc (after reduce).

__device__ __forceinline__ void wave_gather_mean(const float* __restrict__ feat,
                                                 const int* __restrict__ csr,
                                                 int beg, int end, int lane,
                                                 float* sa_row /* [64] LDS */) {
    int eg = lane >> 4;
    int fq = (lane & 15) << 2;
    float a0 = 0.f, a1 = 0.f, a2 = 0.f, a3 = 0.f;
    for (int base = beg; base < end; base += 64) {
        int m = min(64, end - base);
        int idx = (lane < m) ? csr[base + lane] : 0;
        for (int j = 0; j < m; j += 8) {
            int e0 = j + eg;
            int e1 = j + 4 + eg;
            int s0 = __shfl(idx, e0);
            int s1 = __shfl(idx, e1);
            float4 v0 = {0.f, 0.f, 0.f, 0.f};
            float4 v1 = {0.f, 0.f, 0.f, 0.f};
            if (e0 < m) v0 = *(const float4*)(feat + (size_t)s0 * NF + fq);
            if (e1 < m) v1 = *(const float4*)(feat + (size_t)s1 * NF + fq);
            a0 += v0.x + v1.x;
            a1 += v0.y + v1.y;
            a2 += v0.z + v1.z;
            a3 += v0.w + v1.w;
        }
    }
    // reduce across the 4 edge subgroups (lanes differing in bits 4,5)
    a0 += __shfl_xor(a0, 16); a0 += __shfl_xor(a0, 32);
    a1 += __shfl_xor(a1, 16); a1 += __shfl_xor(a1, 32);
    a2 += __shfl_xor(a2, 16); a2 += __shfl_xor(a2, 32);
    a3 += __shfl_xor(a3, 16); a3 += __shfl_xor(a3, 32);
    float inv = 1.0f / (float)max(end - beg, 1);
    if (eg == 0) {
        sa_row[fq + 0] = a0 * inv;
        sa_row[fq + 1] = a1 * inv;
        sa_row[fq + 2] = a2 * inv;
        sa_row[fq + 3] = a3 * inv;
    }
}

// ---------------- gather1: h = relu(x@Ws1 + b1 + (mean x[src])@Wn1) -> A ----------------
// 512 threads = 8 waves, one node per wave.

__global__ __launch_bounds__(512) void gather1_kernel(
        const float* __restrict__ x,
        const int* __restrict__ row_ptr, const int* __restrict__ csr,
        const float* __restrict__ Ws1,  // [64][64]
        const float* __restrict__ Wn1,  // [64][64]
        const float* __restrict__ b1,   // [64]
        float* __restrict__ A,          // out: h (N x 64)
        int n) {
    __shared__ float sWs[NF * NF];
    __shared__ float sWn[NF * NF];
    __shared__ float sx[8][NF];
    __shared__ float sa[8][NF];
    for (int i = threadIdx.x; i < NF * NF; i += blockDim.x) {
        sWs[i] = Ws1[i];
        sWn[i] = Wn1[i];
    }
    __syncthreads();

    int lane = threadIdx.x & 63, wid = threadIdx.x >> 6;
    int node = blockIdx.x * 8 + wid;
    if (node >= n) return;

    float bias = b1[lane];
    sx[wid][lane] = x[(size_t)node * NF + lane];

    int beg = row_ptr[node], end = row_ptr[node + 1];
    wave_gather_mean(x, csr, beg, end, lane, sa[wid]);

    float hacc = bias;
#pragma unroll
    for (int k = 0; k < NF; k++) {
        hacc += sx[wid][k] * sWs[k * NF + lane];
        hacc += sa[wid][k] * sWn[k * NF + lane];
    }
    A[(size_t)node * NF + lane] = fmaxf(hacc, 0.f);
}

// ---------------- gather2: out = h@Ws2 + b2 + (mean h[src])@Wn2 ----------------

__global__ __launch_bounds__(512) void gather2_kernel(
        const float* __restrict__ h,    // region A
        const int* __restrict__ row_ptr, const int* __restrict__ csr,
        const float* __restrict__ Ws2,  // [64][32]
        const float* __restrict__ Wn2,  // [64][32]
        const float* __restrict__ b2,   // [32]
        float* __restrict__ out, int n) {
    __shared__ float sWs[NF * OF];
    __shared__ float sWn[NF * OF];
    __shared__ float sh[8][NF];
    __shared__ float sa[8][NF];
    for (int i = threadIdx.x; i < NF * OF; i += blockDim.x) {
        sWs[i] = Ws2[i];
        sWn[i] = Wn2[i];
    }
    __syncthreads();

    int lane = threadIdx.x & 63, wid = threadIdx.x >> 6;
    int f = lane & 31, half = lane >> 5;
    int node = blockIdx.x * 8 + wid;
    if (node >= n) return;

    float bias = (half == 0) ? b2[f] : 0.f;
    sh[wid][lane] = h[(size_t)node * NF + lane];

    int beg = row_ptr[node], end = row_ptr[node + 1];
    wave_gather_mean(h, csr, beg, end, lane, sa[wid]);

    // split the 64-deep k-sum across the two half-waves, combine with one xor-shuffle
    float oacc = bias;
#pragma unroll
    for (int kk = 0; kk < 32; kk++) {
        int k = half * 32 + kk;
        oacc += sh[wid][k] * sWs[k * OF + f];
        oacc += sa[wid][k] * sWn[k * OF + f];
    }
    oacc += __shfl_xor(oacc, 32);
    if (half == 0) out[(size_t)node * OF + f] = oacc;
}

// ---------------- launch ----------------

extern "C" void kernel_launch(void* const* d_in, const int* in_sizes, int n_in,
                              void* d_out, int out_size, void* d_ws, size_t ws_size,
                              hipStream_t stream) {
    const float* x   = (const float*)d_in[0];
    const int*   src = (const int*)d_in[1];
    const int*   dst = (const int*)d_in[2];
    const float* Ws1 = (const float*)d_in[3];
    const float* Wn1 = (const float*)d_in[4];
    const float* b1  = (const float*)d_in[5];
    const float* Ws2 = (const float*)d_in[6];
    const float* Wn2 = (const float*)d_in[7];
    const float* b2  = (const float*)d_in[8];
    float* out = (float*)d_out;

    int n_nodes = in_sizes[0] / NF;   // 100000
    int n_edges = in_sizes[1];        // 1600000

    // Workspace: cnt/cursor | row_ptr | csr | A (h, N x 64)
    auto align4k = [](size_t v) { return (v + 4095) & ~(size_t)4095; };
    char* ws = (char*)d_ws;
    size_t cnt_b = align4k((size_t)n_nodes * 4);
    size_t rp_b  = align4k(((size_t)n_nodes + 1) * 4);
    size_t csr_b = align4k((size_t)n_edges * 4);
    int* cnt     = (int*)ws;
    int* row_ptr = (int*)(ws + cnt_b);
    int* csr     = (int*)(ws + cnt_b + rp_b);
    float* A     = (float*)(ws + cnt_b + rp_b + csr_b);

    int eblocks = (n_edges + 255) / 256;
    int nblocks = (n_nodes + 7) / 8;

    hipMemsetAsync(cnt, 0, (size_t)n_nodes * 4, stream);
    count_kernel<<<eblocks, 256, 0, stream>>>(dst, cnt, n_edges);
    scan_kernel<<<1, 1024, 0, stream>>>(cnt, row_ptr, n_nodes);
    hipMemsetAsync(cnt, 0, (size_t)n_nodes * 4, stream);   // reuse as cursor
    fill_kernel<<<eblocks, 256, 0, stream>>>(src, dst, row_ptr, cnt, csr, n_edges);

    gather1_kernel<<<nblocks, 512, 0, stream>>>(x, row_ptr, csr, Ws1, Wn1, b1, A, n_nodes);
    gather2_kernel<<<nblocks, 512, 0, stream>>>(A, row_ptr, csr, Ws2, Wn2, b2, out, n_nodes);
}

// Round 4
// 373.738 us; speedup vs baseline: 2.5785x; 1.4018x over previous
//
#include <hip/hip_runtime.h>

#define NF 64     // IN == HID
#define OF 32     // OUT
#define SCAN_CHUNK 1024   // elements per block in hierarchical scan (256 thr x 4)

// ---------------- CSR build ----------------

__global__ void count_kernel(const int* __restrict__ dst, int* __restrict__ cnt, int n_edges) {
    int e = blockIdx.x * blockDim.x + threadIdx.x;
    if (e < n_edges) atomicAdd(&cnt[dst[e]], 1);
}

// Level 1: per-block chunk sums
__global__ void scan_partial_kernel(const int* __restrict__ cnt, int n, int* __restrict__ bsum) {
    __shared__ int red[256];
    int base = blockIdx.x * SCAN_CHUNK + threadIdx.x * 4;
    int s = 0;
#pragma unroll
    for (int j = 0; j < 4; j++) {
        int i = base + j;
        if (i < n) s += cnt[i];
    }
    red[threadIdx.x] = s;
    __syncthreads();
    for (int off = 128; off > 0; off >>= 1) {
        if ((int)threadIdx.x < off) red[threadIdx.x] += red[threadIdx.x + off];
        __syncthreads();
    }
    if (threadIdx.x == 0) bsum[blockIdx.x] = red[0];
}

// Level 2: exclusive scan of block sums (nb <= 256) in one small block
__global__ void scan_bsum_kernel(int* __restrict__ bsum, int nb) {
    __shared__ int sh[256];
    int t = threadIdx.x;
    int v = (t < nb) ? bsum[t] : 0;
    sh[t] = v;
    __syncthreads();
    for (int off = 1; off < 256; off <<= 1) {
        int u = (t >= off) ? sh[t - off] : 0;
        __syncthreads();
        sh[t] += u;
        __syncthreads();
    }
    if (t < nb) bsum[t] = sh[t] - v;   // exclusive
}

// Level 3: block-local exclusive scan + block offset -> row_ptr; last thread writes row_ptr[n]
__global__ void scan_final_kernel(const int* __restrict__ cnt, int n,
                                  const int* __restrict__ bsum,
                                  int* __restrict__ row_ptr) {
    __shared__ int sh[256];
    int t = threadIdx.x;
    int base = blockIdx.x * SCAN_CHUNK + t * 4;
    int v[4];
    int s = 0;
#pragma unroll
    for (int j = 0; j < 4; j++) {
        int i = base + j;
        v[j] = (i < n) ? cnt[i] : 0;
        s += v[j];
    }
    sh[t] = s;
    __syncthreads();
    for (int off = 1; off < 256; off <<= 1) {
        int u = (t >= off) ? sh[t - off] : 0;
        __syncthreads();
        sh[t] += u;
        __syncthreads();
    }
    int run = bsum[blockIdx.x] + sh[t] - s;   // exclusive offset for this thread's quad
#pragma unroll
    for (int j = 0; j < 4; j++) {
        int i = base + j;
        if (i < n) row_ptr[i] = run;
        run += v[j];
    }
    if ((int)blockIdx.x == (int)gridDim.x - 1 && t == 255)
        row_ptr[n] = bsum[blockIdx.x] + sh[255];   // global total
}

__global__ void fill_kernel(const int* __restrict__ src, const int* __restrict__ dst,
                            const int* __restrict__ row_ptr, int* __restrict__ cursor,
                            int* __restrict__ csr, int n_edges) {
    int e = blockIdx.x * blockDim.x + threadIdx.x;
    if (e >= n_edges) return;
    int d = dst[e];
    int slot = atomicAdd(&cursor[d], 1);
    csr[row_ptr[d] + slot] = src[e];
}

// ---------------- gather+GEMM helpers ----------------
// Wave gather layout: eg = lane>>4 (edge subgroup 0..3), fq = (lane&15)*4 (feature quad).
// Each round loads 8 edges (2 x 4) x float4 in flight.

__device__ __forceinline__ void wave_gather_mean(const float* __restrict__ feat,
                                                 const int* __restrict__ csr,
                                                 int beg, int end, int lane,
                                                 float* sa_row /* [64] LDS */) {
    int eg = lane >> 4;
    int fq = (lane & 15) << 2;
    float a0 = 0.f, a1 = 0.f, a2 = 0.f, a3 = 0.f;
    for (int base = beg; base < end; base += 64) {
        int m = min(64, end - base);
        int idx = (lane < m) ? csr[base + lane] : 0;
        for (int j = 0; j < m; j += 8) {
            int e0 = j + eg;
            int e1 = j + 4 + eg;
            int s0 = __shfl(idx, e0);
            int s1 = __shfl(idx, e1);
            float4 v0 = {0.f, 0.f, 0.f, 0.f};
            float4 v1 = {0.f, 0.f, 0.f, 0.f};
            if (e0 < m) v0 = *(const float4*)(feat + (size_t)s0 * NF + fq);
            if (e1 < m) v1 = *(const float4*)(feat + (size_t)s1 * NF + fq);
            a0 += v0.x + v1.x;
            a1 += v0.y + v1.y;
            a2 += v0.z + v1.z;
            a3 += v0.w + v1.w;
        }
    }
    a0 += __shfl_xor(a0, 16); a0 += __shfl_xor(a0, 32);
    a1 += __shfl_xor(a1, 16); a1 += __shfl_xor(a1, 32);
    a2 += __shfl_xor(a2, 16); a2 += __shfl_xor(a2, 32);
    a3 += __shfl_xor(a3, 16); a3 += __shfl_xor(a3, 32);
    float inv = 1.0f / (float)max(end - beg, 1);
    if (eg == 0) {
        sa_row[fq + 0] = a0 * inv;
        sa_row[fq + 1] = a1 * inv;
        sa_row[fq + 2] = a2 * inv;
        sa_row[fq + 3] = a3 * inv;
    }
}

// ---------------- gather1: h = relu(x@Ws1 + b1 + (mean x[src])@Wn1) -> A ----------------

__global__ __launch_bounds__(512) void gather1_kernel(
        const float* __restrict__ x,
        const int* __restrict__ row_ptr, const int* __restrict__ csr,
        const float* __restrict__ Ws1,  // [64][64]
        const float* __restrict__ Wn1,  // [64][64]
        const float* __restrict__ b1,   // [64]
        float* __restrict__ A,          // out: h (N x 64)
        int n) {
    __shared__ float sWs[NF * NF];
    __shared__ float sWn[NF * NF];
    __shared__ float sx[8][NF];
    __shared__ float sa[8][NF];
    for (int i = threadIdx.x; i < NF * NF; i += blockDim.x) {
        sWs[i] = Ws1[i];
        sWn[i] = Wn1[i];
    }
    __syncthreads();

    int lane = threadIdx.x & 63, wid = threadIdx.x >> 6;
    int node = blockIdx.x * 8 + wid;
    if (node >= n) return;

    float bias = b1[lane];
    sx[wid][lane] = x[(size_t)node * NF + lane];

    int beg = row_ptr[node], end = row_ptr[node + 1];
    wave_gather_mean(x, csr, beg, end, lane, sa[wid]);

    float hacc = bias;
#pragma unroll
    for (int k = 0; k < NF; k++) {
        hacc += sx[wid][k] * sWs[k * NF + lane];
        hacc += sa[wid][k] * sWn[k * NF + lane];
    }
    A[(size_t)node * NF + lane] = fmaxf(hacc, 0.f);
}

// ---------------- gather2: out = h@Ws2 + b2 + (mean h[src])@Wn2 ----------------

__global__ __launch_bounds__(512) void gather2_kernel(
        const float* __restrict__ h,    // region A
        const int* __restrict__ row_ptr, const int* __restrict__ csr,
        const float* __restrict__ Ws2,  // [64][32]
        const float* __restrict__ Wn2,  // [64][32]
        const float* __restrict__ b2,   // [32]
        float* __restrict__ out, int n) {
    __shared__ float sWs[NF * OF];
    __shared__ float sWn[NF * OF];
    __shared__ float sh[8][NF];
    __shared__ float sa[8][NF];
    for (int i = threadIdx.x; i < NF * OF; i += blockDim.x) {
        sWs[i] = Ws2[i];
        sWn[i] = Wn2[i];
    }
    __syncthreads();

    int lane = threadIdx.x & 63, wid = threadIdx.x >> 6;
    int f = lane & 31, half = lane >> 5;
    int node = blockIdx.x * 8 + wid;
    if (node >= n) return;

    float bias = (half == 0) ? b2[f] : 0.f;
    sh[wid][lane] = h[(size_t)node * NF + lane];

    int beg = row_ptr[node], end = row_ptr[node + 1];
    wave_gather_mean(h, csr, beg, end, lane, sa[wid]);

    float oacc = bias;
#pragma unroll
    for (int kk = 0; kk < 32; kk++) {
        int k = half * 32 + kk;
        oacc += sh[wid][k] * sWs[k * OF + f];
        oacc += sa[wid][k] * sWn[k * OF + f];
    }
    oacc += __shfl_xor(oacc, 32);
    if (half == 0) out[(size_t)node * OF + f] = oacc;
}

// ---------------- launch ----------------

extern "C" void kernel_launch(void* const* d_in, const int* in_sizes, int n_in,
                              void* d_out, int out_size, void* d_ws, size_t ws_size,
                              hipStream_t stream) {
    const float* x   = (const float*)d_in[0];
    const int*   src = (const int*)d_in[1];
    const int*   dst = (const int*)d_in[2];
    const float* Ws1 = (const float*)d_in[3];
    const float* Wn1 = (const float*)d_in[4];
    const float* b1  = (const float*)d_in[5];
    const float* Ws2 = (const float*)d_in[6];
    const float* Wn2 = (const float*)d_in[7];
    const float* b2  = (const float*)d_in[8];
    float* out = (float*)d_out;

    int n_nodes = in_sizes[0] / NF;   // 100000
    int n_edges = in_sizes[1];        // 1600000

    // Workspace: cnt/cursor | row_ptr | bsum | csr | A (h, N x 64)
    auto align4k = [](size_t v) { return (v + 4095) & ~(size_t)4095; };
    char* ws = (char*)d_ws;
    size_t cnt_b  = align4k((size_t)n_nodes * 4);
    size_t rp_b   = align4k(((size_t)n_nodes + 1) * 4);
    size_t bsum_b = align4k(256 * 4);
    size_t csr_b  = align4k((size_t)n_edges * 4);
    int* cnt     = (int*)ws;
    int* row_ptr = (int*)(ws + cnt_b);
    int* bsum    = (int*)(ws + cnt_b + rp_b);
    int* csr     = (int*)(ws + cnt_b + rp_b + bsum_b);
    float* A     = (float*)(ws + cnt_b + rp_b + bsum_b + csr_b);

    int eblocks = (n_edges + 255) / 256;
    int nblocks = (n_nodes + 7) / 8;
    int sblocks = (n_nodes + SCAN_CHUNK - 1) / SCAN_CHUNK;   // 98 for N=100000 (<=256)

    hipMemsetAsync(cnt, 0, (size_t)n_nodes * 4, stream);
    count_kernel<<<eblocks, 256, 0, stream>>>(dst, cnt, n_edges);
    scan_partial_kernel<<<sblocks, 256, 0, stream>>>(cnt, n_nodes, bsum);
    scan_bsum_kernel<<<1, 256, 0, stream>>>(bsum, sblocks);
    scan_final_kernel<<<sblocks, 256, 0, stream>>>(cnt, n_nodes, bsum, row_ptr);
    hipMemsetAsync(cnt, 0, (size_t)n_nodes * 4, stream);   // reuse as cursor
    fill_kernel<<<eblocks, 256, 0, stream>>>(src, dst, row_ptr, cnt, csr, n_edges);

    gather1_kernel<<<nblocks, 512, 0, stream>>>(x, row_ptr, csr, Ws1, Wn1, b1, A, n_nodes);
    gather2_kernel<<<nblocks, 512, 0, stream>>>(A, row_ptr, csr, Ws2, Wn2, b2, out, n_nodes);
}

// Round 5
// 359.613 us; speedup vs baseline: 2.6797x; 1.0393x over previous
//
#include <hip/hip_runtime.h>

#define NF 64     // IN == HID
#define OF 32     // OUT
#define SCAN_CHUNK 1024

typedef unsigned int uint;
typedef unsigned short ushort;

// ---------------- bf16 helpers ----------------

__device__ __forceinline__ ushort f2bf(float f) {
    uint u = __float_as_uint(f);
    uint r = (u + 0x7fffu + ((u >> 16) & 1u)) >> 16;   // RNE
    return (ushort)r;
}
__device__ __forceinline__ float bf2f(ushort b) { return __uint_as_float(((uint)b) << 16); }
__device__ __forceinline__ float blo(uint u) { return __uint_as_float(u << 16); }
__device__ __forceinline__ float bhi(uint u) { return __uint_as_float(u & 0xffff0000u); }

// ---------------- CSR build ----------------

__global__ void count_kernel(const int* __restrict__ dst, int* __restrict__ cnt, int n_edges) {
    int e = blockIdx.x * blockDim.x + threadIdx.x;
    if (e < n_edges) atomicAdd(&cnt[dst[e]], 1);
}

__global__ void scan_partial_kernel(const int* __restrict__ cnt, int n, int* __restrict__ bsum) {
    __shared__ int red[256];
    int base = blockIdx.x * SCAN_CHUNK + threadIdx.x * 4;
    int s = 0;
#pragma unroll
    for (int j = 0; j < 4; j++) {
        int i = base + j;
        if (i < n) s += cnt[i];
    }
    red[threadIdx.x] = s;
    __syncthreads();
    for (int off = 128; off > 0; off >>= 1) {
        if ((int)threadIdx.x < off) red[threadIdx.x] += red[threadIdx.x + off];
        __syncthreads();
    }
    if (threadIdx.x == 0) bsum[blockIdx.x] = red[0];
}

__global__ void scan_bsum_kernel(int* __restrict__ bsum, int nb) {
    __shared__ int sh[256];
    int t = threadIdx.x;
    int v = (t < nb) ? bsum[t] : 0;
    sh[t] = v;
    __syncthreads();
    for (int off = 1; off < 256; off <<= 1) {
        int u = (t >= off) ? sh[t - off] : 0;
        __syncthreads();
        sh[t] += u;
        __syncthreads();
    }
    if (t < nb) bsum[t] = sh[t] - v;
}

__global__ void scan_final_kernel(const int* __restrict__ cnt, int n,
                                  const int* __restrict__ bsum,
                                  int* __restrict__ row_ptr) {
    __shared__ int sh[256];
    int t = threadIdx.x;
    int base = blockIdx.x * SCAN_CHUNK + t * 4;
    int v[4];
    int s = 0;
#pragma unroll
    for (int j = 0; j < 4; j++) {
        int i = base + j;
        v[j] = (i < n) ? cnt[i] : 0;
        s += v[j];
    }
    sh[t] = s;
    __syncthreads();
    for (int off = 1; off < 256; off <<= 1) {
        int u = (t >= off) ? sh[t - off] : 0;
        __syncthreads();
        sh[t] += u;
        __syncthreads();
    }
    int run = bsum[blockIdx.x] + sh[t] - s;
#pragma unroll
    for (int j = 0; j < 4; j++) {
        int i = base + j;
        if (i < n) row_ptr[i] = run;
        run += v[j];
    }
    if ((int)blockIdx.x == (int)gridDim.x - 1 && t == 255)
        row_ptr[n] = bsum[blockIdx.x] + sh[255];
}

__global__ void fill_kernel(const int* __restrict__ src, const int* __restrict__ dst,
                            const int* __restrict__ row_ptr, int* __restrict__ cursor,
                            int* __restrict__ csr, int n_edges) {
    int e = blockIdx.x * blockDim.x + threadIdx.x;
    if (e >= n_edges) return;
    int d = dst[e];
    int slot = atomicAdd(&cursor[d], 1);
    csr[row_ptr[d] + slot] = src[e];
}

// ---------------- fp32 -> bf16 table ----------------

__global__ void convert_bf16_kernel(const float* __restrict__ in, ushort* __restrict__ out, int n4) {
    int i = blockIdx.x * blockDim.x + threadIdx.x;
    if (i >= n4) return;
    float4 v = *(const float4*)(in + (size_t)i * 4);
    ushort4 o;
    o.x = f2bf(v.x); o.y = f2bf(v.y); o.z = f2bf(v.z); o.w = f2bf(v.w);
    *(ushort4*)(out + (size_t)i * 4) = o;
}

// ---------------- bf16 row gather: 8 lanes/edge, 8 edges/round, 2 rounds in flight ----------------
// Writes mean row into dst[k*2+1] (interleaved (self, agg) pairs).

__device__ __forceinline__ void wave_gather_bf16(const ushort* __restrict__ feat,
                                                 const int* __restrict__ csr,
                                                 int beg, int end, int lane,
                                                 float* __restrict__ dst) {
    int eg = lane >> 3;          // edge subgroup 0..7
    int fo = (lane & 7) << 3;    // feature octet base
    float a[8] = {0.f, 0.f, 0.f, 0.f, 0.f, 0.f, 0.f, 0.f};
    for (int base = beg; base < end; base += 64) {
        int m = min(64, end - base);
        int idx = (lane < m) ? csr[base + lane] : 0;
        for (int j = 0; j < m; j += 16) {
            int e0 = j + eg, e1 = j + 8 + eg;
            int s0 = __shfl(idx, e0);
            int s1 = __shfl(idx, e1);
            uint4 v0 = {0u, 0u, 0u, 0u}, v1 = {0u, 0u, 0u, 0u};
            if (e0 < m) v0 = *(const uint4*)(feat + (size_t)s0 * NF + fo);
            if (e1 < m) v1 = *(const uint4*)(feat + (size_t)s1 * NF + fo);
            a[0] += blo(v0.x) + blo(v1.x);  a[1] += bhi(v0.x) + bhi(v1.x);
            a[2] += blo(v0.y) + blo(v1.y);  a[3] += bhi(v0.y) + bhi(v1.y);
            a[4] += blo(v0.z) + blo(v1.z);  a[5] += bhi(v0.z) + bhi(v1.z);
            a[6] += blo(v0.w) + blo(v1.w);  a[7] += bhi(v0.w) + bhi(v1.w);
        }
    }
#pragma unroll
    for (int i = 0; i < 8; i++) {
        a[i] += __shfl_xor(a[i], 8);
        a[i] += __shfl_xor(a[i], 16);
        a[i] += __shfl_xor(a[i], 32);
    }
    float inv = 1.0f / (float)max(end - beg, 1);
    if (eg == 0) {
#pragma unroll
        for (int i = 0; i < 8; i++) dst[(fo + i) * 2 + 1] = a[i] * inv;
    }
}

// ---------------- gather1: hb = bf16(relu(x@Ws1 + b1 + mean(x[src])@Wn1)) ----------------
// 512 thr = 8 waves; 2 nodes/wave (16/block). Lane = (node = lane>>5, feature pair = (lane&31)*2).

__global__ __launch_bounds__(512) void gather1_kernel(
        const ushort* __restrict__ xb,
        const int* __restrict__ row_ptr, const int* __restrict__ csr,
        const float* __restrict__ Ws1, const float* __restrict__ Wn1,
        const float* __restrict__ b1,
        ushort* __restrict__ hb, int n) {
    __shared__ __align__(16) float sW[NF][NF][2];       // [k][f][{Ws,Wn}] 32 KB
    __shared__ __align__(16) float sxa[8][2][NF][2];    // [wave][node][k][{self,agg}] 8 KB
    for (int i = threadIdx.x; i < NF * NF; i += 512) {
        int k = i >> 6, f = i & 63;
        sW[k][f][0] = Ws1[i];
        sW[k][f][1] = Wn1[i];
    }
    __syncthreads();

    int lane = threadIdx.x & 63, wid = threadIdx.x >> 6;
    int n0 = blockIdx.x * 16 + wid * 2;
    if (n0 >= n) return;
    int n1 = n0 + 1;

    sxa[wid][0][lane][0] = bf2f(xb[(size_t)n0 * NF + lane]);
    if (n1 < n) sxa[wid][1][lane][0] = bf2f(xb[(size_t)n1 * NF + lane]);

    wave_gather_bf16(xb, csr, row_ptr[n0], row_ptr[n0 + 1], lane, &sxa[wid][0][0][0]);
    if (n1 < n)
        wave_gather_bf16(xb, csr, row_ptr[n1], row_ptr[n1 + 1], lane, &sxa[wid][1][0][0]);

    // same-wave LDS write->read; compiler inserts lgkmcnt waits
    int nsel = lane >> 5;
    int fp = (lane & 31) * 2;
    const float* xa_base = &sxa[wid][nsel][0][0];
    float acc_x = b1[fp], acc_y = b1[fp + 1];
#pragma unroll
    for (int k = 0; k < NF; k++) {
        float4 w = *(const float4*)&sW[k][fp][0];   // Ws[fp], Wn[fp], Ws[fp+1], Wn[fp+1]
        float2 xa = *(const float2*)(xa_base + k * 2);
        acc_x += xa.x * w.x + xa.y * w.y;
        acc_y += xa.x * w.z + xa.y * w.w;
    }
    int node = n0 + nsel;
    if (node < n) {
        uint packed = (uint)f2bf(fmaxf(acc_x, 0.f)) | ((uint)f2bf(fmaxf(acc_y, 0.f)) << 16);
        *(uint*)(hb + (size_t)node * NF + fp) = packed;
    }
}

// ---------------- gather2: out = h@Ws2 + b2 + mean(h[src])@Wn2 (fp32 out) ----------------
// 2 nodes/wave. Lane = (node = lane>>5, f = lane&31).

__global__ __launch_bounds__(512) void gather2_kernel(
        const ushort* __restrict__ hb,
        const int* __restrict__ row_ptr, const int* __restrict__ csr,
        const float* __restrict__ Ws2, const float* __restrict__ Wn2,
        const float* __restrict__ b2,
        float* __restrict__ out, int n) {
    __shared__ __align__(16) float sW[NF][OF][2];       // 16 KB
    __shared__ __align__(16) float sha[8][2][NF][2];    // 8 KB
    for (int i = threadIdx.x; i < NF * OF; i += 512) {
        int k = i >> 5, f = i & 31;
        sW[k][f][0] = Ws2[i];
        sW[k][f][1] = Wn2[i];
    }
    __syncthreads();

    int lane = threadIdx.x & 63, wid = threadIdx.x >> 6;
    int n0 = blockIdx.x * 16 + wid * 2;
    if (n0 >= n) return;
    int n1 = n0 + 1;

    sha[wid][0][lane][0] = bf2f(hb[(size_t)n0 * NF + lane]);
    if (n1 < n) sha[wid][1][lane][0] = bf2f(hb[(size_t)n1 * NF + lane]);

    wave_gather_bf16(hb, csr, row_ptr[n0], row_ptr[n0 + 1], lane, &sha[wid][0][0][0]);
    if (n1 < n)
        wave_gather_bf16(hb, csr, row_ptr[n1], row_ptr[n1 + 1], lane, &sha[wid][1][0][0]);

    int nsel = lane >> 5, f = lane & 31;
    const float* xa_base = &sha[wid][nsel][0][0];
    float acc = b2[f];
#pragma unroll
    for (int k = 0; k < NF; k++) {
        float2 w = *(const float2*)&sW[k][f][0];
        float2 xa = *(const float2*)(xa_base + k * 2);
        acc += xa.x * w.x + xa.y * w.y;
    }
    int node = n0 + nsel;
    if (node < n) out[(size_t)node * OF + f] = acc;
}

// ---------------- launch ----------------

extern "C" void kernel_launch(void* const* d_in, const int* in_sizes, int n_in,
                              void* d_out, int out_size, void* d_ws, size_t ws_size,
                              hipStream_t stream) {
    const float* x   = (const float*)d_in[0];
    const int*   src = (const int*)d_in[1];
    const int*   dst = (const int*)d_in[2];
    const float* Ws1 = (const float*)d_in[3];
    const float* Wn1 = (const float*)d_in[4];
    const float* b1  = (const float*)d_in[5];
    const float* Ws2 = (const float*)d_in[6];
    const float* Wn2 = (const float*)d_in[7];
    const float* b2  = (const float*)d_in[8];
    float* out = (float*)d_out;

    int n_nodes = in_sizes[0] / NF;   // 100000
    int n_edges = in_sizes[1];        // 1600000

    // Workspace: cnt/cursor | row_ptr | bsum | csr | xb (bf16) | hb (bf16)
    auto align4k = [](size_t v) { return (v + 4095) & ~(size_t)4095; };
    char* ws = (char*)d_ws;
    size_t cnt_b  = align4k((size_t)n_nodes * 4);
    size_t rp_b   = align4k(((size_t)n_nodes + 1) * 4);
    size_t bsum_b = align4k(256 * 4);
    size_t csr_b  = align4k((size_t)n_edges * 4);
    size_t xb_b   = align4k((size_t)n_nodes * NF * 2);
    int* cnt     = (int*)ws;
    int* row_ptr = (int*)(ws + cnt_b);
    int* bsum    = (int*)(ws + cnt_b + rp_b);
    int* csr     = (int*)(ws + cnt_b + rp_b + bsum_b);
    ushort* xb   = (ushort*)(ws + cnt_b + rp_b + bsum_b + csr_b);
    ushort* hb   = (ushort*)(ws + cnt_b + rp_b + bsum_b + csr_b + xb_b);

    int eblocks = (n_edges + 255) / 256;
    int nblocks = (n_nodes + 15) / 16;
    int sblocks = (n_nodes + SCAN_CHUNK - 1) / SCAN_CHUNK;
    int n4      = n_nodes * NF / 4;
    int cblocks = (n4 + 255) / 256;

    hipMemsetAsync(cnt, 0, (size_t)n_nodes * 4, stream);
    count_kernel<<<eblocks, 256, 0, stream>>>(dst, cnt, n_edges);
    convert_bf16_kernel<<<cblocks, 256, 0, stream>>>(x, xb, n4);
    scan_partial_kernel<<<sblocks, 256, 0, stream>>>(cnt, n_nodes, bsum);
    scan_bsum_kernel<<<1, 256, 0, stream>>>(bsum, sblocks);
    scan_final_kernel<<<sblocks, 256, 0, stream>>>(cnt, n_nodes, bsum, row_ptr);
    hipMemsetAsync(cnt, 0, (size_t)n_nodes * 4, stream);
    fill_kernel<<<eblocks, 256, 0, stream>>>(src, dst, row_ptr, cnt, csr, n_edges);

    gather1_kernel<<<nblocks, 512, 0, stream>>>(xb, row_ptr, csr, Ws1, Wn1, b1, hb, n_nodes);
    gather2_kernel<<<nblocks, 512, 0, stream>>>(hb, row_ptr, csr, Ws2, Wn2, b2, out, n_nodes);
}

// Round 6
// 269.354 us; speedup vs baseline: 3.5777x; 1.3351x over previous
//
#include <hip/hip_runtime.h>

#define NF 64     // IN == HID
#define OF 32     // OUT
#define SCAN_CHUNK 1024

typedef unsigned int uint;
typedef unsigned short ushort;
typedef __attribute__((ext_vector_type(8))) short bf16x8;
typedef __attribute__((ext_vector_type(4))) float f32x4;

// ---------------- bf16 helpers ----------------

__device__ __forceinline__ ushort f2bf(float f) {
    uint u = __float_as_uint(f);
    uint r = (u + 0x7fffu + ((u >> 16) & 1u)) >> 16;   // RNE
    return (ushort)r;
}
__device__ __forceinline__ float blo(uint u) { return __uint_as_float(u << 16); }
__device__ __forceinline__ float bhi(uint u) { return __uint_as_float(u & 0xffff0000u); }

// ---------------- CSR build ----------------

__global__ void count_kernel(const int* __restrict__ dst, int* __restrict__ cnt, int n_edges) {
    int e = blockIdx.x * blockDim.x + threadIdx.x;
    if (e < n_edges) atomicAdd(&cnt[dst[e]], 1);
}

__global__ void scan_partial_kernel(const int* __restrict__ cnt, int n, int* __restrict__ bsum) {
    __shared__ int red[256];
    int base = blockIdx.x * SCAN_CHUNK + threadIdx.x * 4;
    int s = 0;
#pragma unroll
    for (int j = 0; j < 4; j++) {
        int i = base + j;
        if (i < n) s += cnt[i];
    }
    red[threadIdx.x] = s;
    __syncthreads();
    for (int off = 128; off > 0; off >>= 1) {
        if ((int)threadIdx.x < off) red[threadIdx.x] += red[threadIdx.x + off];
        __syncthreads();
    }
    if (threadIdx.x == 0) bsum[blockIdx.x] = red[0];
}

__global__ void scan_bsum_kernel(int* __restrict__ bsum, int nb) {
    __shared__ int sh[256];
    int t = threadIdx.x;
    int v = (t < nb) ? bsum[t] : 0;
    sh[t] = v;
    __syncthreads();
    for (int off = 1; off < 256; off <<= 1) {
        int u = (t >= off) ? sh[t - off] : 0;
        __syncthreads();
        sh[t] += u;
        __syncthreads();
    }
    if (t < nb) bsum[t] = sh[t] - v;
}

__global__ void scan_final_kernel(const int* __restrict__ cnt, int n,
                                  const int* __restrict__ bsum,
                                  int* __restrict__ row_ptr) {
    __shared__ int sh[256];
    int t = threadIdx.x;
    int base = blockIdx.x * SCAN_CHUNK + t * 4;
    int v[4];
    int s = 0;
#pragma unroll
    for (int j = 0; j < 4; j++) {
        int i = base + j;
        v[j] = (i < n) ? cnt[i] : 0;
        s += v[j];
    }
    sh[t] = s;
    __syncthreads();
    for (int off = 1; off < 256; off <<= 1) {
        int u = (t >= off) ? sh[t - off] : 0;
        __syncthreads();
        sh[t] += u;
        __syncthreads();
    }
    int run = bsum[blockIdx.x] + sh[t] - s;
#pragma unroll
    for (int j = 0; j < 4; j++) {
        int i = base + j;
        if (i < n) row_ptr[i] = run;
        run += v[j];
    }
    if ((int)blockIdx.x == (int)gridDim.x - 1 && t == 255)
        row_ptr[n] = bsum[blockIdx.x] + sh[255];
}

__global__ void fill_kernel(const int* __restrict__ src, const int* __restrict__ dst,
                            const int* __restrict__ row_ptr, int* __restrict__ cursor,
                            int* __restrict__ csr, int n_edges) {
    int e = blockIdx.x * blockDim.x + threadIdx.x;
    if (e >= n_edges) return;
    int d = dst[e];
    int slot = atomicAdd(&cursor[d], 1);
    csr[row_ptr[d] + slot] = src[e];
}

// ---------------- fp32 -> bf16 feature table ----------------

__global__ void convert_bf16_kernel(const float* __restrict__ in, ushort* __restrict__ out, int n4) {
    int i = blockIdx.x * blockDim.x + threadIdx.x;
    if (i >= n4) return;
    float4 v = *(const float4*)(in + (size_t)i * 4);
    ushort4 o;
    o.x = f2bf(v.x); o.y = f2bf(v.y); o.z = f2bf(v.z); o.w = f2bf(v.w);
    *(ushort4*)(out + (size_t)i * 4) = o;
}

// ---------------- weight prep: transposed bf16 [col][k], k = concat(Ws rows, Wn rows) ----------------

__global__ void prep_weights_kernel(const float* __restrict__ Ws1, const float* __restrict__ Wn1,
                                    const float* __restrict__ Ws2, const float* __restrict__ Wn2,
                                    ushort* __restrict__ wt1, ushort* __restrict__ wt2) {
    int i = blockIdx.x * blockDim.x + threadIdx.x;
    if (i < NF * 128) {        // wt1: 64 cols x 128 k
        int c = i >> 7, k = i & 127;
        float v = (k < 64) ? Ws1[k * NF + c] : Wn1[(k - 64) * NF + c];
        wt1[i] = f2bf(v);
    }
    if (i < OF * 128) {        // wt2: 32 cols x 128 k
        int c = i >> 7, k = i & 127;
        float v = (k < 64) ? Ws2[k * OF + c] : Wn2[(k - 64) * OF + c];
        wt2[i] = f2bf(v);
    }
}

// ---------------- gather: agg[node] = mean over in-neighbors of feat rows (bf16 in/out) ----------------
// LDS-free. 16 lanes/edge, 8 B (4 feats) per lane; 4 edge-slots; 8 edges in flight.
// Reduce: 2 xor steps x 4 regs. One node per wave, grid-stride.

__global__ __launch_bounds__(256) void gather_kernel(
        const ushort* __restrict__ feat,
        const int* __restrict__ row_ptr, const int* __restrict__ csr,
        ushort* __restrict__ agg, int n) {
    int lane = threadIdx.x & 63;
    int es = lane >> 4;          // edge slot 0..3
    int fq = lane & 15;          // feature quad: feats fq*4 .. fq*4+3
    int wid = blockIdx.x * 4 + (threadIdx.x >> 6);
    int nw = gridDim.x * 4;

    for (int node = wid; node < n; node += nw) {
        int beg = row_ptr[node], end = row_ptr[node + 1];
        float a0 = 0.f, a1 = 0.f, a2 = 0.f, a3 = 0.f;
        for (int base = beg; base < end; base += 64) {
            int m = min(64, end - base);
            int idx = (lane < m) ? csr[base + lane] : 0;
            for (int j = 0; j < m; j += 8) {
                int e0 = j + es, e1 = j + 4 + es;
                int s0 = __shfl(idx, e0);
                int s1 = __shfl(idx, e1);
                uint2 v0 = {0u, 0u}, v1 = {0u, 0u};
                if (e0 < m) v0 = *(const uint2*)(feat + (size_t)s0 * NF + fq * 4);
                if (e1 < m) v1 = *(const uint2*)(feat + (size_t)s1 * NF + fq * 4);
                a0 += blo(v0.x) + blo(v1.x);
                a1 += bhi(v0.x) + bhi(v1.x);
                a2 += blo(v0.y) + blo(v1.y);
                a3 += bhi(v0.y) + bhi(v1.y);
            }
        }
        a0 += __shfl_xor(a0, 16); a0 += __shfl_xor(a0, 32);
        a1 += __shfl_xor(a1, 16); a1 += __shfl_xor(a1, 32);
        a2 += __shfl_xor(a2, 16); a2 += __shfl_xor(a2, 32);
        a3 += __shfl_xor(a3, 16); a3 += __shfl_xor(a3, 32);
        if (es == 0) {
            float inv = 1.0f / (float)max(end - beg, 1);
            uint2 o;
            o.x = (uint)f2bf(a0 * inv) | ((uint)f2bf(a1 * inv) << 16);
            o.y = (uint)f2bf(a2 * inv) | ((uint)f2bf(a3 * inv) << 16);
            *(uint2*)(agg + (size_t)node * NF + fq * 4) = o;
        }
    }
}

// ---------------- gemm1: hb = bf16(relu([xb|aggx] @ Wt1^T + b1)), MFMA 16x16x32 ----------------
// One 16-node tile per wave iter. B-frags (weights) in registers. Zero LDS.
// Frag maps (gfx950, verified C/D): A: row=lane&15, k=(lane>>4)*8+i ; B: col=lane&15, same k ;
// C: col=lane&15, row=(lane>>4)*4+reg.

__global__ __launch_bounds__(256) void gemm1_kernel(
        const ushort* __restrict__ xb, const ushort* __restrict__ aggx,
        const ushort* __restrict__ wt,   // [64][128] bf16, wt[c][k]
        const float* __restrict__ bias,  // [64]
        ushort* __restrict__ hb, int n, int ntiles) {
    int lane = threadIdx.x & 63;
    int col = lane & 15, kg = lane >> 4;
    int wid = blockIdx.x * 4 + (threadIdx.x >> 6);
    int nw = gridDim.x * 4;

    bf16x8 bfrag[4][4];
#pragma unroll
    for (int ct = 0; ct < 4; ct++)
#pragma unroll
        for (int kt = 0; kt < 4; kt++)
            bfrag[ct][kt] = *(const bf16x8*)(wt + ((ct * 16 + col) * 128 + kt * 32 + kg * 8));
    float bias_v[4];
#pragma unroll
    for (int ct = 0; ct < 4; ct++) bias_v[ct] = bias[ct * 16 + col];

    for (int tile = wid; tile < ntiles; tile += nw) {
        int r0 = tile * 16;
        int row = min(r0 + col, n - 1);
        const ushort* xrow = xb + (size_t)row * NF;
        const ushort* arow = aggx + (size_t)row * NF;
        bf16x8 afrag[4];
        afrag[0] = *(const bf16x8*)(xrow + kg * 8);
        afrag[1] = *(const bf16x8*)(xrow + 32 + kg * 8);
        afrag[2] = *(const bf16x8*)(arow + kg * 8);
        afrag[3] = *(const bf16x8*)(arow + 32 + kg * 8);
#pragma unroll
        for (int ct = 0; ct < 4; ct++) {
            f32x4 c = {0.f, 0.f, 0.f, 0.f};
#pragma unroll
            for (int kt = 0; kt < 4; kt++)
                c = __builtin_amdgcn_mfma_f32_16x16x32_bf16(afrag[kt], bfrag[ct][kt], c, 0, 0, 0);
#pragma unroll
            for (int rg = 0; rg < 4; rg++) {
                int ro = r0 + kg * 4 + rg;
                if (ro < n) {
                    float v = c[rg] + bias_v[ct];
                    hb[(size_t)ro * NF + ct * 16 + col] = f2bf(fmaxf(v, 0.f));
                }
            }
        }
    }
}

// ---------------- gemm2: out = [hb|aggh] @ Wt2^T + b2 (fp32 out, no relu) ----------------

__global__ __launch_bounds__(256) void gemm2_kernel(
        const ushort* __restrict__ hb, const ushort* __restrict__ aggh,
        const ushort* __restrict__ wt,   // [32][128] bf16
        const float* __restrict__ bias,  // [32]
        float* __restrict__ out, int n, int ntiles) {
    int lane = threadIdx.x & 63;
    int col = lane & 15, kg = lane >> 4;
    int wid = blockIdx.x * 4 + (threadIdx.x >> 6);
    int nw = gridDim.x * 4;

    bf16x8 bfrag[2][4];
#pragma unroll
    for (int ct = 0; ct < 2; ct++)
#pragma unroll
        for (int kt = 0; kt < 4; kt++)
            bfrag[ct][kt] = *(const bf16x8*)(wt + ((ct * 16 + col) * 128 + kt * 32 + kg * 8));
    float bias_v[2];
#pragma unroll
    for (int ct = 0; ct < 2; ct++) bias_v[ct] = bias[ct * 16 + col];

    for (int tile = wid; tile < ntiles; tile += nw) {
        int r0 = tile * 16;
        int row = min(r0 + col, n - 1);
        const ushort* hrow = hb + (size_t)row * NF;
        const ushort* arow = aggh + (size_t)row * NF;
        bf16x8 afrag[4];
        afrag[0] = *(const bf16x8*)(hrow + kg * 8);
        afrag[1] = *(const bf16x8*)(hrow + 32 + kg * 8);
        afrag[2] = *(const bf16x8*)(arow + kg * 8);
        afrag[3] = *(const bf16x8*)(arow + 32 + kg * 8);
#pragma unroll
        for (int ct = 0; ct < 2; ct++) {
            f32x4 c = {0.f, 0.f, 0.f, 0.f};
#pragma unroll
            for (int kt = 0; kt < 4; kt++)
                c = __builtin_amdgcn_mfma_f32_16x16x32_bf16(afrag[kt], bfrag[ct][kt], c, 0, 0, 0);
#pragma unroll
            for (int rg = 0; rg < 4; rg++) {
                int ro = r0 + kg * 4 + rg;
                if (ro < n) out[(size_t)ro * OF + ct * 16 + col] = c[rg] + bias_v[ct];
            }
        }
    }
}

// ---------------- launch ----------------

extern "C" void kernel_launch(void* const* d_in, const int* in_sizes, int n_in,
                              void* d_out, int out_size, void* d_ws, size_t ws_size,
                              hipStream_t stream) {
    const float* x   = (const float*)d_in[0];
    const int*   src = (const int*)d_in[1];
    const int*   dst = (const int*)d_in[2];
    const float* Ws1 = (const float*)d_in[3];
    const float* Wn1 = (const float*)d_in[4];
    const float* b1  = (const float*)d_in[5];
    const float* Ws2 = (const float*)d_in[6];
    const float* Wn2 = (const float*)d_in[7];
    const float* b2  = (const float*)d_in[8];
    float* out = (float*)d_out;

    int n_nodes = in_sizes[0] / NF;   // 100000
    int n_edges = in_sizes[1];        // 1600000

    // Workspace: cnt | row_ptr | bsum | csr | xb | hb | agg (shared aggx/aggh) | wt1 | wt2
    auto align4k = [](size_t v) { return (v + 4095) & ~(size_t)4095; };
    char* ws = (char*)d_ws;
    size_t cnt_b  = align4k((size_t)n_nodes * 4);
    size_t rp_b   = align4k(((size_t)n_nodes + 1) * 4);
    size_t bsum_b = align4k(256 * 4);
    size_t csr_b  = align4k((size_t)n_edges * 4);
    size_t xb_b   = align4k((size_t)n_nodes * NF * 2);
    size_t hb_b   = xb_b;
    size_t agg_b  = xb_b;
    int* cnt     = (int*)ws;
    int* row_ptr = (int*)(ws + cnt_b);
    int* bsum    = (int*)(ws + cnt_b + rp_b);
    int* csr     = (int*)(ws + cnt_b + rp_b + bsum_b);
    ushort* xb   = (ushort*)(ws + cnt_b + rp_b + bsum_b + csr_b);
    ushort* hb   = (ushort*)(ws + cnt_b + rp_b + bsum_b + csr_b + xb_b);
    ushort* agg  = (ushort*)(ws + cnt_b + rp_b + bsum_b + csr_b + xb_b + hb_b);
    ushort* wt1  = (ushort*)(ws + cnt_b + rp_b + bsum_b + csr_b + xb_b + hb_b + agg_b);
    ushort* wt2  = wt1 + NF * 128;

    int eblocks = (n_edges + 255) / 256;
    int sblocks = (n_nodes + SCAN_CHUNK - 1) / SCAN_CHUNK;
    int n4      = n_nodes * NF / 4;
    int cblocks = (n4 + 255) / 256;
    int ntiles  = (n_nodes + 15) / 16;
    int gblocks = 2048;    // gather: 8192 waves, grid-stride over nodes
    int mblocks = 512;     // gemm: 2048 waves, grid-stride over tiles

    // CSR build + conversions (independent work interleaved)
    hipMemsetAsync(cnt, 0, (size_t)n_nodes * 4, stream);
    count_kernel<<<eblocks, 256, 0, stream>>>(dst, cnt, n_edges);
    convert_bf16_kernel<<<cblocks, 256, 0, stream>>>(x, xb, n4);
    prep_weights_kernel<<<(NF * 128 + 255) / 256, 256, 0, stream>>>(Ws1, Wn1, Ws2, Wn2, wt1, wt2);
    scan_partial_kernel<<<sblocks, 256, 0, stream>>>(cnt, n_nodes, bsum);
    scan_bsum_kernel<<<1, 256, 0, stream>>>(bsum, sblocks);
    scan_final_kernel<<<sblocks, 256, 0, stream>>>(cnt, n_nodes, bsum, row_ptr);
    hipMemsetAsync(cnt, 0, (size_t)n_nodes * 4, stream);   // reuse as cursor
    fill_kernel<<<eblocks, 256, 0, stream>>>(src, dst, row_ptr, cnt, csr, n_edges);

    // Layer 1
    gather_kernel<<<gblocks, 256, 0, stream>>>(xb, row_ptr, csr, agg, n_nodes);
    gemm1_kernel<<<mblocks, 256, 0, stream>>>(xb, agg, wt1, b1, hb, n_nodes, ntiles);

    // Layer 2 (reuses agg region)
    gather_kernel<<<gblocks, 256, 0, stream>>>(hb, row_ptr, csr, agg, n_nodes);
    gemm2_kernel<<<mblocks, 256, 0, stream>>>(hb, agg, wt2, b2, out, n_nodes, ntiles);
}

// Round 7
// 144.776 us; speedup vs baseline: 6.6563x; 1.8605x over previous
//
#include <hip/hip_runtime.h>

#define NF 64     // IN == HID
#define OF 32     // OUT

#define NPB 512        // nodes per bucket (power of 2)
#define NPB_SHIFT 9
#define BCAP 12288     // max staged edges per bucket (mean 8192, sigma ~91 -> never hit)
#define BIN_CHUNK 4096 // edges per binning block (256 thr x 16)

typedef unsigned int uint;
typedef unsigned short ushort;
typedef __attribute__((ext_vector_type(8))) short bf16x8;
typedef __attribute__((ext_vector_type(4))) float f32x4;

// ---------------- bf16 helpers ----------------

__device__ __forceinline__ ushort f2bf(float f) {
    uint u = __float_as_uint(f);
    uint r = (u + 0x7fffu + ((u >> 16) & 1u)) >> 16;   // RNE
    return (ushort)r;
}
__device__ __forceinline__ float blo(uint u) { return __uint_as_float(u << 16); }
__device__ __forceinline__ float bhi(uint u) { return __uint_as_float(u & 0xffff0000u); }

// ---------------- CSR build: bucketed two-pass, no global scatter ----------------

// Pass 1: bin edges into 512-node buckets. Stage word = (dst_local << 17) | src.
__global__ __launch_bounds__(256) void binning_kernel(
        const int* __restrict__ src, const int* __restrict__ dst, int n_edges,
        int* __restrict__ gcur, uint* __restrict__ stage) {
    __shared__ int hist[256];
    __shared__ int base[256];
    __shared__ int rank[256];
    int t = threadIdx.x;
    hist[t] = 0;
    rank[t] = 0;
    __syncthreads();

    int e0 = blockIdx.x * BIN_CHUNK;
    uint my_pack[16];
    int my_b[16];
#pragma unroll
    for (int j = 0; j < 16; j++) {
        int e = e0 + j * 256 + t;
        if (e < n_edges) {
            int s = src[e];
            int d = dst[e];
            int b = d >> NPB_SHIFT;
            my_b[j] = b;
            my_pack[j] = ((uint)(d & (NPB - 1)) << 17) | (uint)s;
            atomicAdd(&hist[b], 1);
        } else {
            my_b[j] = -1;
        }
    }
    __syncthreads();
    if (hist[t] > 0) base[t] = atomicAdd(&gcur[t], hist[t]);
    __syncthreads();
#pragma unroll
    for (int j = 0; j < 16; j++) {
        if (my_b[j] >= 0) {
            int r = atomicAdd(&rank[my_b[j]], 1);
            int pos = base[my_b[j]] + r;
            if (pos < BCAP) stage[(size_t)my_b[j] * BCAP + pos] = my_pack[j];
        }
    }
}

// Pass 1.5: exclusive scan of bucket counts (nb <= 256) -> bucket_base
__global__ void bucket_scan_kernel(const int* __restrict__ gcnt, int* __restrict__ bucket_base, int nb) {
    __shared__ int sh[256];
    int t = threadIdx.x;
    int v = (t < nb) ? gcnt[t] : 0;
    sh[t] = v;
    __syncthreads();
    for (int off = 1; off < 256; off <<= 1) {
        int u = (t >= off) ? sh[t - off] : 0;
        __syncthreads();
        sh[t] += u;
        __syncthreads();
    }
    if (t < nb) bucket_base[t] = sh[t] - v;   // exclusive
    if (t == 255) bucket_base[nb] = sh[255];  // total
}

// Pass 2: one block per bucket. Per-node counts + scan in LDS -> row_ptr;
// scatter srcs inside LDS; stream segment out coalesced.
__global__ __launch_bounds__(256) void build_kernel(
        const uint* __restrict__ stage, const int* __restrict__ gcnt,
        const int* __restrict__ bucket_base,
        int* __restrict__ row_ptr, int* __restrict__ csr, int n, int nb) {
    __shared__ int ncnt[NPB];
    __shared__ int lcur[NPB];
    __shared__ int psum[256];
    __shared__ int lcsr[BCAP];

    int b = blockIdx.x;
    int t = threadIdx.x;
    int cnt = min(gcnt[b], BCAP);
    int node0 = b << NPB_SHIFT;
    int gbase = bucket_base[b];
    const uint* st = stage + (size_t)b * BCAP;

    ncnt[t] = 0;
    ncnt[t + 256] = 0;
    __syncthreads();
    for (int i = t; i < cnt; i += 256)
        atomicAdd(&ncnt[st[i] >> 17], 1);
    __syncthreads();

    // exclusive scan over 512 node counts (2 per thread)
    int a0 = ncnt[2 * t], a1 = ncnt[2 * t + 1];
    psum[t] = a0 + a1;
    __syncthreads();
    for (int off = 1; off < 256; off <<= 1) {
        int u = (t >= off) ? psum[t - off] : 0;
        __syncthreads();
        psum[t] += u;
        __syncthreads();
    }
    int excl = (t == 0) ? 0 : psum[t - 1];
    int off0 = excl, off1 = excl + a0;
    int g0 = node0 + 2 * t, g1 = node0 + 2 * t + 1;
    if (g0 < n) row_ptr[g0] = gbase + off0;
    if (g1 < n) row_ptr[g1] = gbase + off1;
    lcur[2 * t] = off0;
    lcur[2 * t + 1] = off1;
    __syncthreads();

    for (int i = t; i < cnt; i += 256) {
        uint p = st[i];
        int slot = atomicAdd(&lcur[p >> 17], 1);
        lcsr[slot] = (int)(p & 0x1FFFFu);
    }
    __syncthreads();
    for (int i = t; i < cnt; i += 256)
        csr[gbase + i] = lcsr[i];

    if (b == nb - 1 && t == 0) row_ptr[n] = gbase + cnt;
}

// ---------------- fp32 -> bf16 feature table ----------------

__global__ void convert_bf16_kernel(const float* __restrict__ in, ushort* __restrict__ out, int n4) {
    int i = blockIdx.x * blockDim.x + threadIdx.x;
    if (i >= n4) return;
    float4 v = *(const float4*)(in + (size_t)i * 4);
    ushort4 o;
    o.x = f2bf(v.x); o.y = f2bf(v.y); o.z = f2bf(v.z); o.w = f2bf(v.w);
    *(ushort4*)(out + (size_t)i * 4) = o;
}

// ---------------- weight prep: transposed bf16 [col][k], k = concat(Ws rows, Wn rows) ----------------

__global__ void prep_weights_kernel(const float* __restrict__ Ws1, const float* __restrict__ Wn1,
                                    const float* __restrict__ Ws2, const float* __restrict__ Wn2,
                                    ushort* __restrict__ wt1, ushort* __restrict__ wt2) {
    int i = blockIdx.x * blockDim.x + threadIdx.x;
    if (i < NF * 128) {        // wt1: 64 cols x 128 k
        int c = i >> 7, k = i & 127;
        float v = (k < 64) ? Ws1[k * NF + c] : Wn1[(k - 64) * NF + c];
        wt1[i] = f2bf(v);
    }
    if (i < OF * 128) {        // wt2: 32 cols x 128 k
        int c = i >> 7, k = i & 127;
        float v = (k < 64) ? Ws2[k * OF + c] : Wn2[(k - 64) * OF + c];
        wt2[i] = f2bf(v);
    }
}

// ---------------- gather: agg[node] = mean over in-neighbors of feat rows (bf16 in/out) ----------------
// LDS-free. 16 lanes/edge, 8 B (4 feats) per lane; 4 edge-slots; 8 edges in flight.

__global__ __launch_bounds__(256) void gather_kernel(
        const ushort* __restrict__ feat,
        const int* __restrict__ row_ptr, const int* __restrict__ csr,
        ushort* __restrict__ agg, int n) {
    int lane = threadIdx.x & 63;
    int es = lane >> 4;          // edge slot 0..3
    int fq = lane & 15;          // feature quad: feats fq*4 .. fq*4+3
    int wid = blockIdx.x * 4 + (threadIdx.x >> 6);
    int nw = gridDim.x * 4;

    for (int node = wid; node < n; node += nw) {
        int beg = row_ptr[node], end = row_ptr[node + 1];
        float a0 = 0.f, a1 = 0.f, a2 = 0.f, a3 = 0.f;
        for (int base = beg; base < end; base += 64) {
            int m = min(64, end - base);
            int idx = (lane < m) ? csr[base + lane] : 0;
            for (int j = 0; j < m; j += 8) {
                int e0 = j + es, e1 = j + 4 + es;
                int s0 = __shfl(idx, e0);
                int s1 = __shfl(idx, e1);
                uint2 v0 = {0u, 0u}, v1 = {0u, 0u};
                if (e0 < m) v0 = *(const uint2*)(feat + (size_t)s0 * NF + fq * 4);
                if (e1 < m) v1 = *(const uint2*)(feat + (size_t)s1 * NF + fq * 4);
                a0 += blo(v0.x) + blo(v1.x);
                a1 += bhi(v0.x) + bhi(v1.x);
                a2 += blo(v0.y) + blo(v1.y);
                a3 += bhi(v0.y) + bhi(v1.y);
            }
        }
        a0 += __shfl_xor(a0, 16); a0 += __shfl_xor(a0, 32);
        a1 += __shfl_xor(a1, 16); a1 += __shfl_xor(a1, 32);
        a2 += __shfl_xor(a2, 16); a2 += __shfl_xor(a2, 32);
        a3 += __shfl_xor(a3, 16); a3 += __shfl_xor(a3, 32);
        if (es == 0) {
            float inv = 1.0f / (float)max(end - beg, 1);
            uint2 o;
            o.x = (uint)f2bf(a0 * inv) | ((uint)f2bf(a1 * inv) << 16);
            o.y = (uint)f2bf(a2 * inv) | ((uint)f2bf(a3 * inv) << 16);
            *(uint2*)(agg + (size_t)node * NF + fq * 4) = o;
        }
    }
}

// ---------------- gemm1: hb = bf16(relu([xb|aggx] @ Wt1^T + b1)), MFMA 16x16x32 ----------------

__global__ __launch_bounds__(256) void gemm1_kernel(
        const ushort* __restrict__ xb, const ushort* __restrict__ aggx,
        const ushort* __restrict__ wt,   // [64][128] bf16, wt[c][k]
        const float* __restrict__ bias,  // [64]
        ushort* __restrict__ hb, int n, int ntiles) {
    int lane = threadIdx.x & 63;
    int col = lane & 15, kg = lane >> 4;
    int wid = blockIdx.x * 4 + (threadIdx.x >> 6);
    int nw = gridDim.x * 4;

    bf16x8 bfrag[4][4];
#pragma unroll
    for (int ct = 0; ct < 4; ct++)
#pragma unroll
        for (int kt = 0; kt < 4; kt++)
            bfrag[ct][kt] = *(const bf16x8*)(wt + ((ct * 16 + col) * 128 + kt * 32 + kg * 8));
    float bias_v[4];
#pragma unroll
    for (int ct = 0; ct < 4; ct++) bias_v[ct] = bias[ct * 16 + col];

    for (int tile = wid; tile < ntiles; tile += nw) {
        int r0 = tile * 16;
        int row = min(r0 + col, n - 1);
        const ushort* xrow = xb + (size_t)row * NF;
        const ushort* arow = aggx + (size_t)row * NF;
        bf16x8 afrag[4];
        afrag[0] = *(const bf16x8*)(xrow + kg * 8);
        afrag[1] = *(const bf16x8*)(xrow + 32 + kg * 8);
        afrag[2] = *(const bf16x8*)(arow + kg * 8);
        afrag[3] = *(const bf16x8*)(arow + 32 + kg * 8);
#pragma unroll
        for (int ct = 0; ct < 4; ct++) {
            f32x4 c = {0.f, 0.f, 0.f, 0.f};
#pragma unroll
            for (int kt = 0; kt < 4; kt++)
                c = __builtin_amdgcn_mfma_f32_16x16x32_bf16(afrag[kt], bfrag[ct][kt], c, 0, 0, 0);
#pragma unroll
            for (int rg = 0; rg < 4; rg++) {
                int ro = r0 + kg * 4 + rg;
                if (ro < n) {
                    float v = c[rg] + bias_v[ct];
                    hb[(size_t)ro * NF + ct * 16 + col] = f2bf(fmaxf(v, 0.f));
                }
            }
        }
    }
}

// ---------------- gemm2: out = [hb|aggh] @ Wt2^T + b2 (fp32 out, no relu) ----------------

__global__ __launch_bounds__(256) void gemm2_kernel(
        const ushort* __restrict__ hb, const ushort* __restrict__ aggh,
        const ushort* __restrict__ wt,   // [32][128] bf16
        const float* __restrict__ bias,  // [32]
        float* __restrict__ out, int n, int ntiles) {
    int lane = threadIdx.x & 63;
    int col = lane & 15, kg = lane >> 4;
    int wid = blockIdx.x * 4 + (threadIdx.x >> 6);
    int nw = gridDim.x * 4;

    bf16x8 bfrag[2][4];
#pragma unroll
    for (int ct = 0; ct < 2; ct++)
#pragma unroll
        for (int kt = 0; kt < 4; kt++)
            bfrag[ct][kt] = *(const bf16x8*)(wt + ((ct * 16 + col) * 128 + kt * 32 + kg * 8));
    float bias_v[2];
#pragma unroll
    for (int ct = 0; ct < 2; ct++) bias_v[ct] = bias[ct * 16 + col];

    for (int tile = wid; tile < ntiles; tile += nw) {
        int r0 = tile * 16;
        int row = min(r0 + col, n - 1);
        const ushort* hrow = hb + (size_t)row * NF;
        const ushort* arow = aggh + (size_t)row * NF;
        bf16x8 afrag[4];
        afrag[0] = *(const bf16x8*)(hrow + kg * 8);
        afrag[1] = *(const bf16x8*)(hrow + 32 + kg * 8);
        afrag[2] = *(const bf16x8*)(arow + kg * 8);
        afrag[3] = *(const bf16x8*)(arow + 32 + kg * 8);
#pragma unroll
        for (int ct = 0; ct < 2; ct++) {
            f32x4 c = {0.f, 0.f, 0.f, 0.f};
#pragma unroll
            for (int kt = 0; kt < 4; kt++)
                c = __builtin_amdgcn_mfma_f32_16x16x32_bf16(afrag[kt], bfrag[ct][kt], c, 0, 0, 0);
#pragma unroll
            for (int rg = 0; rg < 4; rg++) {
                int ro = r0 + kg * 4 + rg;
                if (ro < n) out[(size_t)ro * OF + ct * 16 + col] = c[rg] + bias_v[ct];
            }
        }
    }
}

// ---------------- launch ----------------

extern "C" void kernel_launch(void* const* d_in, const int* in_sizes, int n_in,
                              void* d_out, int out_size, void* d_ws, size_t ws_size,
                              hipStream_t stream) {
    const float* x   = (const float*)d_in[0];
    const int*   src = (const int*)d_in[1];
    const int*   dst = (const int*)d_in[2];
    const float* Ws1 = (const float*)d_in[3];
    const float* Wn1 = (const float*)d_in[4];
    const float* b1  = (const float*)d_in[5];
    const float* Ws2 = (const float*)d_in[6];
    const float* Wn2 = (const float*)d_in[7];
    const float* b2  = (const float*)d_in[8];
    float* out = (float*)d_out;

    int n_nodes = in_sizes[0] / NF;   // 100000
    int n_edges = in_sizes[1];        // 1600000
    int nb = (n_nodes + NPB - 1) >> NPB_SHIFT;   // 196 buckets

    // Workspace: gcur(256) | bucket_base(257) | row_ptr(n+1) | csr(E) | xb | hb | agg | wt1 | wt2
    // stage (nb*BCAP uints, 9.6 MB) aliases the agg region (12.8 MB): stage is dead before
    // the first gather writes agg.
    auto align4k = [](size_t v) { return (v + 4095) & ~(size_t)4095; };
    char* ws = (char*)d_ws;
    size_t gcur_b = align4k(256 * 4);
    size_t bb_b   = align4k(257 * 4);
    size_t rp_b   = align4k(((size_t)n_nodes + 1) * 4);
    size_t csr_b  = align4k((size_t)n_edges * 4);
    size_t xb_b   = align4k((size_t)n_nodes * NF * 2);
    size_t hb_b   = xb_b;
    size_t agg_b  = xb_b;
    int* gcur        = (int*)ws;
    int* bucket_base = (int*)(ws + gcur_b);
    int* row_ptr     = (int*)(ws + gcur_b + bb_b);
    int* csr         = (int*)(ws + gcur_b + bb_b + rp_b);
    ushort* xb       = (ushort*)(ws + gcur_b + bb_b + rp_b + csr_b);
    ushort* hb       = (ushort*)(ws + gcur_b + bb_b + rp_b + csr_b + xb_b);
    ushort* agg      = (ushort*)(ws + gcur_b + bb_b + rp_b + csr_b + xb_b + hb_b);
    uint*   stage    = (uint*)agg;   // alias
    ushort* wt1      = (ushort*)(ws + gcur_b + bb_b + rp_b + csr_b + xb_b + hb_b + agg_b);
    ushort* wt2      = wt1 + NF * 128;

    int bin_blocks = (n_edges + BIN_CHUNK - 1) / BIN_CHUNK;   // 391
    int n4      = n_nodes * NF / 4;
    int cblocks = (n4 + 255) / 256;
    int ntiles  = (n_nodes + 15) / 16;
    int gblocks = 2048;    // gather: 8192 waves, grid-stride over nodes
    int mblocks = 512;     // gemm: 2048 waves, grid-stride over tiles

    // CSR build (bucketed) + conversions
    hipMemsetAsync(gcur, 0, 256 * 4, stream);
    convert_bf16_kernel<<<cblocks, 256, 0, stream>>>(x, xb, n4);
    prep_weights_kernel<<<(NF * 128 + 255) / 256, 256, 0, stream>>>(Ws1, Wn1, Ws2, Wn2, wt1, wt2);
    binning_kernel<<<bin_blocks, 256, 0, stream>>>(src, dst, n_edges, gcur, stage);
    bucket_scan_kernel<<<1, 256, 0, stream>>>(gcur, bucket_base, nb);
    build_kernel<<<nb, 256, 0, stream>>>(stage, gcur, bucket_base, row_ptr, csr, n_nodes, nb);

    // Layer 1
    gather_kernel<<<gblocks, 256, 0, stream>>>(xb, row_ptr, csr, agg, n_nodes);
    gemm1_kernel<<<mblocks, 256, 0, stream>>>(xb, agg, wt1, b1, hb, n_nodes, ntiles);

    // Layer 2 (agg region reused after stage is dead)
    gather_kernel<<<gblocks, 256, 0, stream>>>(hb, row_ptr, csr, agg, n_nodes);
    gemm2_kernel<<<mblocks, 256, 0, stream>>>(hb, agg, wt2, b2, out, n_nodes, ntiles);
}